// Round 4
// baseline (123.085 us; speedup 1.0000x reference)
//
#include <hip/hip_runtime.h>

#define TILE_NODES 32
#define NBLOCKS 512

typedef __attribute__((ext_vector_type(4))) float f32x4;
typedef __attribute__((ext_vector_type(8))) __bf16 bf16x8;
typedef __attribute__((ext_vector_type(8))) unsigned short u16x8;

__device__ __forceinline__ unsigned short f2bf(float f) {
    unsigned u = __builtin_bit_cast(unsigned, f);
    u += 0x7fffu + ((u >> 16) & 1u);   // RNE
    return (unsigned short)(u >> 16);
}

// B fragments, fragment-major, weights pre-scaled.
// elem i = ((T*4 + kt)*8 + ct)*512 + lane*8 + j
// value  = scale_T * W_T[k = kt*32 + (lane>>4)*8 + j][col = ct*16 + (lane&15)]
// T: 0=alpha*W1, 1=alpha*W2, 2=alpha*W3, 3=(alpha/sqrt3)*W4
__global__ void build_bfrag_kernel(const float* __restrict__ W1,
                                   const float* __restrict__ W2,
                                   const float* __restrict__ W3,
                                   const float* __restrict__ W4,
                                   unsigned short* __restrict__ bfrag) {
    const float ALPHA = 0.0625f;                       // 1/sqrt(2*128)
    const float A3    = 0.0625f * 0.57735026918962576f;
    int i = blockIdx.x * 256 + threadIdx.x;            // 0..65535
    int j  = i & 7;
    int l  = (i >> 3) & 63;
    int ct = (i >> 9) & 7;
    int kt = (i >> 12) & 3;
    int T  = (i >> 14) & 3;
    int k   = kt * 32 + ((l >> 4) & 3) * 8 + j;
    int col = ct * 16 + (l & 15);
    const float* W = (T == 0) ? W1 : (T == 1) ? W2 : (T == 2) ? W3 : W4;
    float s = (T == 3) ? A3 : ALPHA;
    bfrag[i] = f2bf(s * W[k * 128 + col]);
}

__global__ __launch_bounds__(512, 2)
void o3tp_kernel(const float* __restrict__ x, const float* __restrict__ y,
                 const float* __restrict__ bias,
                 const unsigned short* __restrict__ bfrag,
                 float* __restrict__ out, int tiles_per_block) {
    // 2 buffers x (4 chunks x 32 nodes x 128 bf16) = 64 KB.
    // chunk slab: c*8192; row: node*256; byte-in-row: (k*2) ^ ((node&7)<<4)
    __shared__ __align__(16) unsigned char smem[65536];
    const int tid = threadIdx.x;
    const int w   = tid >> 6;     // wave id == column tile ct
    const int l   = tid & 63;
    const int lk  = l >> 4;
    const int lr  = l & 15;

    // ---- B fragments: resident in registers for the whole kernel ----
    u16x8 bq[4][4];
    #pragma unroll
    for (int T = 0; T < 4; ++T)
        #pragma unroll
        for (int kt = 0; kt < 4; ++kt)
            bq[T][kt] = *(const u16x8*)(bfrag + (((T * 4 + kt) * 8 + w) << 9) + l * 8);
    const float bias_v = bias[w * 16 + lr];

    // staging assignment: one (node, k-octet) per thread
    const int n_  = tid >> 4;     // 0..31
    const int G   = tid & 15;     // 0..15
    const int swz = (n_ & 7) << 4;

    const long tile0 = (long)blockIdx.x * tiles_per_block;

    f32x4 X0a, X0b, Ta, Tb, Tc, Td, Te, Tf;
    auto LOADS = [&](long tile) {
        const float* bp = x + (tile * TILE_NODES + n_) * 512;
        X0a = *(const f32x4*)(bp + 8 * G);
        X0b = *(const f32x4*)(bp + 8 * G + 4);
        const float* tp = bp + 128 + 24 * G;
        Ta = *(const f32x4*)(tp);      Tb = *(const f32x4*)(tp + 4);
        Tc = *(const f32x4*)(tp + 8);  Td = *(const f32x4*)(tp + 12);
        Te = *(const f32x4*)(tp + 16); Tf = *(const f32x4*)(tp + 20);
    };
    auto WRITE = [&](int buf) {
        unsigned char* base = smem + buf * 32768 + n_ * 256 + ((16 * G) ^ swz);
        bf16x8 v;
        v[0] = (__bf16)X0a[0]; v[1] = (__bf16)X0a[1]; v[2] = (__bf16)X0a[2]; v[3] = (__bf16)X0a[3];
        v[4] = (__bf16)X0b[0]; v[5] = (__bf16)X0b[1]; v[6] = (__bf16)X0b[2]; v[7] = (__bf16)X0b[3];
        *(bf16x8*)(base) = v;                                  // chunk 0 (x0)
        float t[24] = {Ta[0],Ta[1],Ta[2],Ta[3], Tb[0],Tb[1],Tb[2],Tb[3],
                       Tc[0],Tc[1],Tc[2],Tc[3], Td[0],Td[1],Td[2],Td[3],
                       Te[0],Te[1],Te[2],Te[3], Tf[0],Tf[1],Tf[2],Tf[3]};
        #pragma unroll
        for (int i3 = 0; i3 < 3; ++i3) {                       // chunks 1..3 (x1_i)
            bf16x8 u;
            #pragma unroll
            for (int up = 0; up < 8; ++up) u[up] = (__bf16)t[3 * up + i3];
            *(bf16x8*)(base + (i3 + 1) * 8192) = u;
        }
    };

    // deferred-store buffers: final output values for the previous tile
    float ob0[2][4];          // out0 [m][j]
    float ob1[2][4][3];       // out1 [m][j][i]
    const int c0 = w * 16 + lr;

    auto STORE_OUT = [&](long tile) {
        const long nb = tile * TILE_NODES;
        #pragma unroll
        for (int m = 0; m < 2; ++m)
            #pragma unroll
            for (int j = 0; j < 4; ++j) {
                const int nl = m * 16 + lk * 4 + j;
                float* rp = out + (nb + nl) * 512;
                rp[c0] = ob0[m][j];
                rp[128 + 3 * c0 + 0] = ob1[m][j][0];
                rp[128 + 3 * c0 + 1] = ob1[m][j][1];
                rp[128 + 3 * c0 + 2] = ob1[m][j][2];
            }
    };

    // prologue
    LOADS(tile0);
    WRITE(0);

    for (int it = 0; it < tiles_per_block; ++it) {
        const long tile = tile0 + it;
        __syncthreads();                              // buf[it&1] ready for all waves
        if (it + 1 < tiles_per_block) LOADS(tile + 1);   // next x-tile in flight
        if (it > 0) STORE_OUT(tile - 1);                 // prev outputs: issue now, drain next barrier

        // ---- MFMA: 8 unscaled products for this wave's 16-col slice ----
        const unsigned char* ab = smem + (it & 1) * 32768;
        f32x4 M1[2] = {}, M2[2] = {}, M3[3][2] = {}, M4[3][2] = {};
        #pragma unroll
        for (int c = 0; c < 4; ++c) {
            u16x8 ar[2][4];
            #pragma unroll
            for (int m = 0; m < 2; ++m)
                #pragma unroll
                for (int kt = 0; kt < 4; ++kt)
                    ar[m][kt] = *(const u16x8*)(ab + c * 8192 + (m * 16 + lr) * 256
                                                + ((kt * 64 + lk * 16) ^ ((l & 7) << 4)));
            #pragma unroll
            for (int m = 0; m < 2; ++m)
                #pragma unroll
                for (int kt = 0; kt < 4; ++kt) {
                    if (c == 0) {
                        M1[m] = __builtin_amdgcn_mfma_f32_16x16x32_bf16(
                            __builtin_bit_cast(bf16x8, ar[m][kt]),
                            __builtin_bit_cast(bf16x8, bq[0][kt]), M1[m], 0, 0, 0);
                        M2[m] = __builtin_amdgcn_mfma_f32_16x16x32_bf16(
                            __builtin_bit_cast(bf16x8, ar[m][kt]),
                            __builtin_bit_cast(bf16x8, bq[1][kt]), M2[m], 0, 0, 0);
                    } else {
                        M3[c - 1][m] = __builtin_amdgcn_mfma_f32_16x16x32_bf16(
                            __builtin_bit_cast(bf16x8, ar[m][kt]),
                            __builtin_bit_cast(bf16x8, bq[2][kt]), M3[c - 1][m], 0, 0, 0);
                        M4[c - 1][m] = __builtin_amdgcn_mfma_f32_16x16x32_bf16(
                            __builtin_bit_cast(bf16x8, ar[m][kt]),
                            __builtin_bit_cast(bf16x8, bq[3][kt]), M4[c - 1][m], 0, 0, 0);
                    }
                }
        }

        // ---- LDS write for next tile first (ds latency hides under combine) ----
        if (it + 1 < tiles_per_block) WRITE((it + 1) & 1);

        // ---- per-node y-combination into registers (stores deferred) ----
        const long nb = tile * TILE_NODES;
        #pragma unroll
        for (int m = 0; m < 2; ++m)
            #pragma unroll
            for (int j = 0; j < 4; ++j) {
                const int nl = m * 16 + lk * 4 + j;
                const f32x4 yv = *(const f32x4*)(y + (nb + nl) * 4);   // 16-lane broadcast
                ob0[m][j] = yv[0] * M1[m][j] + yv[1] * M4[0][m][j]
                          + yv[2] * M4[1][m][j] + yv[3] * M4[2][m][j] + bias_v;
                ob1[m][j][0] = yv[1] * M2[m][j] + yv[0] * M3[0][m][j];
                ob1[m][j][1] = yv[2] * M2[m][j] + yv[0] * M3[1][m][j];
                ob1[m][j][2] = yv[3] * M2[m][j] + yv[0] * M3[2][m][j];
            }
    }
    // final tile's outputs
    STORE_OUT(tile0 + tiles_per_block - 1);
}

extern "C" void kernel_launch(void* const* d_in, const int* in_sizes, int n_in,
                              void* d_out, int out_size, void* d_ws, size_t ws_size,
                              hipStream_t stream) {
    const float* x  = (const float*)d_in[0];
    const float* y  = (const float*)d_in[1];
    const float* W1 = (const float*)d_in[2];
    const float* W2 = (const float*)d_in[3];
    const float* W3 = (const float*)d_in[4];
    const float* W4 = (const float*)d_in[5];
    const float* b  = (const float*)d_in[6];
    float* out = (float*)d_out;
    unsigned short* bfrag = (unsigned short*)d_ws;   // 65536 bf16 = 128 KB

    int n_nodes = in_sizes[0] / 512;
    int ntiles  = n_nodes / TILE_NODES;
    int tpb     = ntiles / NBLOCKS;                  // 8 for N=131072

    hipLaunchKernelGGL(build_bfrag_kernel, dim3(256), dim3(256), 0, stream,
                       W1, W2, W3, W4, bfrag);
    hipLaunchKernelGGL(o3tp_kernel, dim3(NBLOCKS), dim3(512), 0, stream,
                       x, y, b, bfrag, out, tpb);
}

// Round 5
// 118.473 us; speedup vs baseline: 1.0389x; 1.0389x over previous
//
#include <hip/hip_runtime.h>

#define TILE_NODES 32
#define NBLOCKS 256

typedef __attribute__((ext_vector_type(4))) float f32x4;
typedef __attribute__((ext_vector_type(3))) float f32x3;
typedef __attribute__((ext_vector_type(8))) __bf16 bf16x8;
typedef __attribute__((ext_vector_type(8))) unsigned short u16x8;

__device__ __forceinline__ unsigned short f2bf(float f) {
    unsigned u = __builtin_bit_cast(unsigned, f);
    u += 0x7fffu + ((u >> 16) & 1u);   // RNE
    return (unsigned short)(u >> 16);
}

// B fragments, fragment-major, weights pre-scaled.
// elem i = ((T*4 + kt)*8 + ct)*512 + lane*8 + j
// value  = scale_T * W_T[k = kt*32 + (lane>>4)*8 + j][col = ct*16 + (lane&15)]
// T: 0=alpha*W1, 1=alpha*W2, 2=alpha*W3, 3=(alpha/sqrt3)*W4
__global__ void build_bfrag_kernel(const float* __restrict__ W1,
                                   const float* __restrict__ W2,
                                   const float* __restrict__ W3,
                                   const float* __restrict__ W4,
                                   unsigned short* __restrict__ bfrag) {
    const float ALPHA = 0.0625f;                       // 1/sqrt(2*128)
    const float A3    = 0.0625f * 0.57735026918962576f;
    int i = blockIdx.x * 256 + threadIdx.x;            // 0..65535
    int j  = i & 7;
    int l  = (i >> 3) & 63;
    int ct = (i >> 9) & 7;
    int kt = (i >> 12) & 3;
    int T  = (i >> 14) & 3;
    int k   = kt * 32 + ((l >> 4) & 3) * 8 + j;
    int col = ct * 16 + (l & 15);
    const float* W = (T == 0) ? W1 : (T == 1) ? W2 : (T == 2) ? W3 : W4;
    float s = (T == 3) ? A3 : ALPHA;
    bfrag[i] = f2bf(s * W[k * 128 + col]);
}

__global__ __launch_bounds__(512, 2)
void o3tp_kernel(const float* __restrict__ x, const float* __restrict__ y,
                 const float* __restrict__ bias,
                 const unsigned short* __restrict__ bfrag,
                 float* __restrict__ out, int tiles_per_block) {
    // 0..65535 : x double-buffer (2 x 4 chunks x 32 nodes x 128 bf16)
    // 65536+   : y slab (tpb*32 nodes x 4 f32 = 8 KB at tpb=16)
    __shared__ __align__(16) unsigned char smem[73728];
    const int tid = threadIdx.x;
    const int w   = tid >> 6;     // wave id == column tile ct
    const int l   = tid & 63;
    const int lk  = l >> 4;
    const int lr  = l & 15;

    // ---- B fragments: resident in registers for the whole kernel ----
    u16x8 bq[4][4];
    #pragma unroll
    for (int T = 0; T < 4; ++T)
        #pragma unroll
        for (int kt = 0; kt < 4; ++kt)
            bq[T][kt] = *(const u16x8*)(bfrag + (((T * 4 + kt) * 8 + w) << 9) + l * 8);
    const float bias_v = bias[w * 16 + lr];

    // staging assignment: one (node, k-octet) per thread
    const int n_  = tid >> 4;     // 0..31
    const int G   = tid & 15;     // 0..15
    const int swz = (n_ & 7) << 4;

    const long tile0 = (long)blockIdx.x * tiles_per_block;
    const long node0 = tile0 * TILE_NODES;

    // ---- y: stage whole block's y into LDS once (combine then only touches lgkmcnt) ----
    float* yslab = (float*)(smem + 65536);
    for (int i = tid; i < tiles_per_block * TILE_NODES; i += 512)
        *(f32x4*)(yslab + i * 4) = *(const f32x4*)(y + (node0 + i) * 4);

    f32x4 X0a, X0b, Ta, Tb, Tc, Td, Te, Tf;
    auto LOADS = [&](long tile) {
        const float* bp = x + (tile * TILE_NODES + n_) * 512;
        X0a = *(const f32x4*)(bp + 8 * G);
        X0b = *(const f32x4*)(bp + 8 * G + 4);
        const float* tp = bp + 128 + 24 * G;
        Ta = *(const f32x4*)(tp);      Tb = *(const f32x4*)(tp + 4);
        Tc = *(const f32x4*)(tp + 8);  Td = *(const f32x4*)(tp + 12);
        Te = *(const f32x4*)(tp + 16); Tf = *(const f32x4*)(tp + 20);
    };
    auto WRITE = [&](int buf) {
        unsigned char* base = smem + buf * 32768 + n_ * 256 + ((16 * G) ^ swz);
        bf16x8 v;
        v[0] = (__bf16)X0a[0]; v[1] = (__bf16)X0a[1]; v[2] = (__bf16)X0a[2]; v[3] = (__bf16)X0a[3];
        v[4] = (__bf16)X0b[0]; v[5] = (__bf16)X0b[1]; v[6] = (__bf16)X0b[2]; v[7] = (__bf16)X0b[3];
        *(bf16x8*)(base) = v;                                  // chunk 0 (x0)
        float t[24] = {Ta[0],Ta[1],Ta[2],Ta[3], Tb[0],Tb[1],Tb[2],Tb[3],
                       Tc[0],Tc[1],Tc[2],Tc[3], Td[0],Td[1],Td[2],Td[3],
                       Te[0],Te[1],Te[2],Te[3], Tf[0],Tf[1],Tf[2],Tf[3]};
        #pragma unroll
        for (int i3 = 0; i3 < 3; ++i3) {                       // chunks 1..3 (x1_i)
            bf16x8 u;
            #pragma unroll
            for (int up = 0; up < 8; ++up) u[up] = (__bf16)t[3 * up + i3];
            *(bf16x8*)(base + (i3 + 1) * 8192) = u;
        }
    };

    const int c0 = w * 16 + lr;

    // ---- prologue: tile0 staged, tile1 loads in flight across the barrier ----
    LOADS(tile0);
    WRITE(0);
    if (tiles_per_block > 1) LOADS(tile0 + 1);
    asm volatile("s_waitcnt lgkmcnt(0)" ::: "memory");
    __builtin_amdgcn_s_barrier();

    for (int it = 0; it < tiles_per_block; ++it) {
        const long tile = tile0 + it;

        // ---- MFMA: 8 unscaled products for this wave's 16-col slice ----
        const unsigned char* ab = smem + (it & 1) * 32768;
        f32x4 M1[2] = {}, M2[2] = {}, M3[3][2] = {}, M4[3][2] = {};
        #pragma unroll
        for (int c = 0; c < 4; ++c) {
            u16x8 ar[2][4];
            #pragma unroll
            for (int m = 0; m < 2; ++m)
                #pragma unroll
                for (int kt = 0; kt < 4; ++kt)
                    ar[m][kt] = *(const u16x8*)(ab + c * 8192 + (m * 16 + lr) * 256
                                                + ((kt * 64 + lk * 16) ^ ((l & 7) << 4)));
            #pragma unroll
            for (int m = 0; m < 2; ++m)
                #pragma unroll
                for (int kt = 0; kt < 4; ++kt) {
                    if (c == 0) {
                        M1[m] = __builtin_amdgcn_mfma_f32_16x16x32_bf16(
                            __builtin_bit_cast(bf16x8, ar[m][kt]),
                            __builtin_bit_cast(bf16x8, bq[0][kt]), M1[m], 0, 0, 0);
                        M2[m] = __builtin_amdgcn_mfma_f32_16x16x32_bf16(
                            __builtin_bit_cast(bf16x8, ar[m][kt]),
                            __builtin_bit_cast(bf16x8, bq[1][kt]), M2[m], 0, 0, 0);
                    } else {
                        M3[c - 1][m] = __builtin_amdgcn_mfma_f32_16x16x32_bf16(
                            __builtin_bit_cast(bf16x8, ar[m][kt]),
                            __builtin_bit_cast(bf16x8, bq[2][kt]), M3[c - 1][m], 0, 0, 0);
                        M4[c - 1][m] = __builtin_amdgcn_mfma_f32_16x16x32_bf16(
                            __builtin_bit_cast(bf16x8, ar[m][kt]),
                            __builtin_bit_cast(bf16x8, bq[3][kt]), M4[c - 1][m], 0, 0, 0);
                    }
                }
        }

        // ---- consume in-flight x-loads (counted vmcnt: stores never gate this),
        //      then immediately put the NEXT tile's loads in flight (full-tile window)
        if (it + 1 < tiles_per_block) WRITE((it + 1) & 1);
        if (it + 2 < tiles_per_block) LOADS(tile + 2);
        __builtin_amdgcn_sched_barrier(0);   // keep the stores below AFTER the loads above

        // ---- per-node y-combination (y from LDS), stores issued from fresh regs ----
        #pragma unroll
        for (int m = 0; m < 2; ++m)
            #pragma unroll
            for (int j = 0; j < 4; ++j) {
                const int nl = m * 16 + lk * 4 + j;
                const f32x4 yv = *(const f32x4*)(yslab + (it * TILE_NODES + nl) * 4);
                float* rp = out + (node0 + it * TILE_NODES + nl) * 512;
                rp[c0] = yv[0] * M1[m][j] + yv[1] * M4[0][m][j]
                       + yv[2] * M4[1][m][j] + yv[3] * M4[2][m][j] + bias_v;
                f32x3 o1;
                o1[0] = yv[1] * M2[m][j] + yv[0] * M3[0][m][j];
                o1[1] = yv[2] * M2[m][j] + yv[0] * M3[1][m][j];
                o1[2] = yv[3] * M2[m][j] + yv[0] * M3[2][m][j];
                *(f32x3*)(rp + 128 + 3 * c0) = o1;
            }

        // ---- raw barrier: LDS-only drain; global stores stay in flight across it ----
        if (it + 1 < tiles_per_block) {
            asm volatile("s_waitcnt lgkmcnt(0)" ::: "memory");
            __builtin_amdgcn_s_barrier();
        }
    }
}

extern "C" void kernel_launch(void* const* d_in, const int* in_sizes, int n_in,
                              void* d_out, int out_size, void* d_ws, size_t ws_size,
                              hipStream_t stream) {
    const float* x  = (const float*)d_in[0];
    const float* y  = (const float*)d_in[1];
    const float* W1 = (const float*)d_in[2];
    const float* W2 = (const float*)d_in[3];
    const float* W3 = (const float*)d_in[4];
    const float* W4 = (const float*)d_in[5];
    const float* b  = (const float*)d_in[6];
    float* out = (float*)d_out;
    unsigned short* bfrag = (unsigned short*)d_ws;   // 65536 bf16 = 128 KB

    int n_nodes = in_sizes[0] / 512;
    int ntiles  = n_nodes / TILE_NODES;
    int tpb     = ntiles / NBLOCKS;                  // 16 for N=131072

    hipLaunchKernelGGL(build_bfrag_kernel, dim3(256), dim3(256), 0, stream,
                       W1, W2, W3, W4, bfrag);
    hipLaunchKernelGGL(o3tp_kernel, dim3(NBLOCKS), dim3(512), 0, stream,
                       x, y, b, bfrag, out, tpb);
}